// Round 7
// baseline (834.899 us; speedup 1.0000x reference)
//
#include <hip/hip_runtime.h>
#include <math.h>

// Problem constants: B=16384, IN=128, H=512, Y=32, K=8
// out = sqrtm(Sigma_inv + 1e-6 I) per batch, [16384,32,32] fp32

typedef float v2f __attribute__((ext_vector_type(2)));

// ---------------------------------------------------------------------------
// Generic tiled fp32 GEMM: C[M,N] = act(A[M,K] @ B[K,N] + bias)
// ACT: 0=none, 1=relu, 2=softplus -> store 1/(D*D) with D = softplus(z)+1e-3
// ---------------------------------------------------------------------------
template <int ACT>
__global__ __launch_bounds__(256) void gemm_act(const float* __restrict__ A,
                                                const float* __restrict__ Bm,
                                                const float* __restrict__ bias,
                                                float* __restrict__ C,
                                                int M, int N, int K) {
  __shared__ float As[16][68];
  __shared__ float Bs[16][68];
  const int tid = threadIdx.x;
  const int bm = blockIdx.y * 64;
  const int bn = blockIdx.x * 64;
  const int tx = tid & 15, ty = tid >> 4;
  const int arow = tid >> 2, acol4 = (tid & 3) << 2;
  const int brow = tid >> 4, bcol4 = (tid & 15) << 2;
  float acc[4][4] = {};

  for (int k0 = 0; k0 < K; k0 += 16) {
    float4 av = *(const float4*)(A + (size_t)(bm + arow) * K + (k0 + acol4));
    As[acol4 + 0][arow] = av.x;
    As[acol4 + 1][arow] = av.y;
    As[acol4 + 2][arow] = av.z;
    As[acol4 + 3][arow] = av.w;
    float4 bv = make_float4(0.f, 0.f, 0.f, 0.f);
    if (bn + bcol4 < N)
      bv = *(const float4*)(Bm + (size_t)(k0 + brow) * N + (bn + bcol4));
    *(float4*)&Bs[brow][bcol4] = bv;
    __syncthreads();
#pragma unroll
    for (int k = 0; k < 16; ++k) {
      float ar[4], br[4];
#pragma unroll
      for (int i = 0; i < 4; ++i) ar[i] = As[k][(ty << 2) + i];
#pragma unroll
      for (int j = 0; j < 4; ++j) br[j] = Bs[k][(tx << 2) + j];
#pragma unroll
      for (int i = 0; i < 4; ++i)
#pragma unroll
        for (int j = 0; j < 4; ++j) acc[i][j] = fmaf(ar[i], br[j], acc[i][j]);
    }
    __syncthreads();
  }

#pragma unroll
  for (int i = 0; i < 4; ++i) {
    int row = bm + (ty << 2) + i;
#pragma unroll
    for (int j = 0; j < 4; ++j) {
      int col = bn + (tx << 2) + j;
      if (col < N) {
        float v = acc[i][j] + bias[col];
        if (ACT == 1) v = fmaxf(v, 0.f);
        if (ACT == 2) {
          float sp = fmaxf(v, 0.f) + log1pf(expf(-fabsf(v)));
          float D = sp + 1e-3f;
          v = 1.f / (D * D);
        }
        C[(size_t)row * N + col] = v;
      }
    }
  }
}

// ---------------------------------------------------------------------------
// Packed fp32 primitives (CDNA2+ v_pk_* VOP3P). asm "v" constraints force
// arch-VGPR residency: kills both AGPR shuttling and bpermute remat.
// ---------------------------------------------------------------------------
__device__ __forceinline__ v2f pk_mul(v2f a, v2f b) {
  v2f d;
  asm("v_pk_mul_f32 %0, %1, %2" : "=v"(d) : "v"(a), "v"(b));
  return d;
}
__device__ __forceinline__ v2f pk_fma(v2f a, v2f b, v2f c) {
  v2f d;
  asm("v_pk_fma_f32 %0, %1, %2, %3" : "=v"(d) : "v"(a), "v"(b), "v"(c));
  return d;
}
__device__ __forceinline__ v2f pk_add(v2f a, v2f b) {
  v2f d;
  asm("v_pk_add_f32 %0, %1, %2" : "=v"(d) : "v"(a), "v"(b));
  return d;
}
#define PIN2(x) asm("" : "+v"(x))

__device__ __forceinline__ float bperm1(int addr, float v) {
  return __int_as_float(__builtin_amdgcn_ds_bpermute(addr, __float_as_int(v)));
}

__device__ __forceinline__ float dotcols(const v2f* a, const v2f* b) {
  v2f d0 = {0.f, 0.f}, d1 = {0.f, 0.f}, d2 = {0.f, 0.f}, d3 = {0.f, 0.f};
#pragma unroll
  for (int k = 0; k < 16; k += 4) {
    d0 = pk_fma(a[k + 0], b[k + 0], d0);
    d1 = pk_fma(a[k + 1], b[k + 1], d1);
    d2 = pk_fma(a[k + 2], b[k + 2], d2);
    d3 = pk_fma(a[k + 3], b[k + 3], d3);
  }
  v2f st = pk_add(pk_add(d0, d1), pk_add(d2, d3));
  return st.x + st.y;
}

// Rotate columns O (own) and P (resident partner copy). Canonical roles:
// if isp, O is the p-column. p' = c p - s q ; q' = s p + c q.
// UPDP=false skips the P-side update (dead copy after last use in a meeting;
// verified bit-exact vs the partner lane's mirrored computation).
template <bool UPDP>
__device__ __forceinline__ void crossrot(v2f* O, float& nO, v2f* P, float& nP,
                                         bool isp) {
  const float apq = dotcols(O, P);
  const float app = isp ? nO : nP;
  const float aqq = isp ? nP : nO;
  const bool big = fabsf(apq) > 1e-30f;
  const float sapq = big ? apq : 1.f;
  const float tau = (aqq - app) * 0.5f * __builtin_amdgcn_rcpf(sapq);
  float t = copysignf(
      __builtin_amdgcn_rcpf(fabsf(tau) + sqrtf(fmaf(tau, tau, 1.f))), tau);
  t = big ? t : 0.f;
  const float c = __builtin_amdgcn_rsqf(fmaf(t, t, 1.f));
  const float s = t * c;
  const float se = isp ? -s : s;
  const v2f cc = {c, c};
  const v2f vse = {se, se};
  const v2f nse = {-se, -se};
#pragma unroll
  for (int k = 0; k < 16; ++k) {
    v2f o = O[k];
    O[k] = pk_fma(vse, P[k], pk_mul(cc, o));
    if (UPDP) P[k] = pk_fma(nse, o, pk_mul(cc, P[k]));
  }
  const float d = t * apq;
  nO = fmaxf(isp ? nO - d : nO + d, 0.f);
  if (UPDP) nP = fmaxf(isp ? nP + d : nP - d, 0.f);
}

// ---------------------------------------------------------------------------
// Block one-sided Jacobi: 2 columns/lane, 16 lanes/batch, 4 batches/wave.
// 7 sweeps (6 fails: worst-case batch tail needs the 7th, absmax 0.14>0.12).
// ---------------------------------------------------------------------------
__global__ __launch_bounds__(64, 2) void woodbury_sqrtm_blk(
    const float* __restrict__ invD2g, const float* __restrict__ Vg,
    float* __restrict__ out) {
  const int lane = threadIdx.x;
  const int q = lane >> 4;   // batch slot within the wave
  const int l = lane & 15;   // lane within the 16-lane batch group
  const int b = blockIdx.x * 4 + q;
  const int ca = 2 * l;      // own columns ca, ca+1

  // LDS: setup region and epilogue FT alias.
  __shared__ __align__(16) char lds[17408];
  float* adS = (float*)lds;              // [4][32]        @0     512
  float* Vs = (float*)(lds + 512);       // [4][32][8]     @512   4096
  double* Md = (double*)(lds + 4608);    // [4][8][9] f64  @4608  2304
  float* Uf = (float*)(lds + 6912);      // [4][32][8]     @6912  4096
  float* FT = (float*)lds;               // [4][32][34]    @0     17408 (epi)

  // ---- load inputs: invD2 pair + V rows ca, ca+1 ----
  const float2 adp = *(const float2*)(invD2g + (size_t)b * 32 + ca);
  const float ada = adp.x, adb = adp.y;
  adS[q * 32 + ca] = ada;
  adS[q * 32 + ca + 1] = adb;
  const float4 va0 = *(const float4*)(Vg + (size_t)b * 256 + ca * 8);
  const float4 va1 = *(const float4*)(Vg + (size_t)b * 256 + ca * 8 + 4);
  const float4 vb0 = *(const float4*)(Vg + (size_t)b * 256 + ca * 8 + 8);
  const float4 vb1 = *(const float4*)(Vg + (size_t)b * 256 + ca * 8 + 12);
  *(float4*)(Vs + (q * 32 + ca) * 8) = va0;
  *(float4*)(Vs + (q * 32 + ca) * 8 + 4) = va1;
  *(float4*)(Vs + (q * 32 + ca + 1) * 8) = vb0;
  *(float4*)(Vs + (q * 32 + ca + 1) * 8 + 4) = vb1;
  __syncthreads();

  // ---- M = I + V^T diag(invD2) V (8x8; lane: row r, 4 cols; f64 acc) ----
  {
    const int r = l >> 1, c0 = (l & 1) * 4;
    double m0 = 0, m1 = 0, m2 = 0, m3 = 0;
    const float* vq = Vs + q * 256;
    const float* aq = adS + q * 32;
    for (int y = 0; y < 32; ++y) {
      const double pr = (double)vq[y * 8 + r] * (double)aq[y];
      m0 += pr * (double)vq[y * 8 + c0 + 0];
      m1 += pr * (double)vq[y * 8 + c0 + 1];
      m2 += pr * (double)vq[y * 8 + c0 + 2];
      m3 += pr * (double)vq[y * 8 + c0 + 3];
    }
    double* Mq = Md + q * 72;
    Mq[r * 9 + c0 + 0] = m0 + ((r == c0 + 0) ? 1.0 : 0.0);
    Mq[r * 9 + c0 + 1] = m1 + ((r == c0 + 1) ? 1.0 : 0.0);
    Mq[r * 9 + c0 + 2] = m2 + ((r == c0 + 2) ? 1.0 : 0.0);
    Mq[r * 9 + c0 + 3] = m3 + ((r == c0 + 3) ? 1.0 : 0.0);
  }
  __syncthreads();

  // ---- Cholesky M = L L^T in place (lower), serial per batch (f64) ----
  if (l == 0) {
    double* M = Md + q * 72;
    for (int k = 0; k < 8; ++k) {
      double d = M[k * 9 + k];
      for (int i = 0; i < k; ++i) {
        const double lv = M[k * 9 + i];
        d -= lv * lv;
      }
      const double lkk = sqrt(fmax(d, 1e-30));
      M[k * 9 + k] = lkk;
      const double inv = 1.0 / lkk;
      for (int r = k + 1; r < 8; ++r) {
        double v = M[r * 9 + k];
        for (int i = 0; i < k; ++i) v -= M[r * 9 + i] * M[k * 9 + i];
        M[r * 9 + k] = v * inv;
      }
    }
  }
  __syncthreads();

  // ---- U rows ca, ca+1: solve U L^T = W (W row = V row * invD2) f64 ----
  float ua[8], ub[8];
  {
    const double* L = Md + q * 72;
    const float wa[8] = {va0.x * ada, va0.y * ada, va0.z * ada, va0.w * ada,
                         va1.x * ada, va1.y * ada, va1.z * ada, va1.w * ada};
    const float wb[8] = {vb0.x * adb, vb0.y * adb, vb0.z * adb, vb0.w * adb,
                         vb1.x * adb, vb1.y * adb, vb1.z * adb, vb1.w * adb};
    double ta[8], tb[8];
#pragma unroll
    for (int jj = 0; jj < 8; ++jj) {
      double sa = (double)wa[jj], sb = (double)wb[jj];
      for (int i = 0; i < jj; ++i) {
        const double lv = L[jj * 9 + i];
        sa -= ta[i] * lv;
        sb -= tb[i] * lv;
      }
      const double inv = 1.0 / L[jj * 9 + jj];
      ta[jj] = sa * inv;
      tb[jj] = sb * inv;
      ua[jj] = (float)ta[jj];
      ub[jj] = (float)tb[jj];
    }
    float* ur = Uf + q * 256;
#pragma unroll
    for (int k = 0; k < 8; ++k) {
      ur[ca * 8 + k] = ua[k];
      ur[(ca + 1) * 8 + k] = ub[k];
    }
  }
  __syncthreads();

  // ---- G columns ca, ca+1: G[i][j] = d_ij(invD2_i+eps) - (U U^T)_ij ----
  v2f gA[16], gB[16];
  {
    const float* uq = Uf + q * 256;
    for (int i = 0; i < 32; ++i) {
      const float* ui = uq + i * 8;
      float sa = 0.f, sb = 0.f;
#pragma unroll
      for (int k = 0; k < 8; ++k) {
        sa = fmaf(ui[k], ua[k], sa);
        sb = fmaf(ui[k], ub[k], sb);
      }
      float gva = -sa, gvb = -sb;
      if (i == ca) gva += ada + 1e-6f;
      if (i == ca + 1) gvb += adb + 1e-6f;
      if (i & 1) {
        gA[i >> 1].y = gva;
        gB[i >> 1].y = gvb;
      } else {
        gA[i >> 1].x = gva;
        gB[i >> 1].x = gvb;
      }
    }
  }
  __syncthreads();  // setup LDS dead; FT aliasing safe after this point

  // ---- block Jacobi: 7 sweeps x 15 meetings ----
  const int self4 = lane << 2;
  float nA = 0.f, nB = 0.f;
  for (int sweep = 0; sweep < 7; ++sweep) {
    nA = dotcols(gA, gA);  // fresh norms kill incremental drift
    nB = dotcols(gB, gB);
    for (int m = 1; m < 16; ++m) {
      // own-pair rotation BEFORE the exchange (both lanes do their own)
      crossrot<true>(gA, nA, gB, nB, true);
      // pull partner block once; pin so it cannot be re-materialized
      const int pa4 = self4 ^ (m << 2);
      v2f pA[16], pB[16];
#pragma unroll
      for (int k = 0; k < 16; ++k) {
        v2f t0, t1;
        t0.x = bperm1(pa4, gA[k].x);
        t0.y = bperm1(pa4, gA[k].y);
        PIN2(t0);
        pA[k] = t0;
        t1.x = bperm1(pa4, gB[k].x);
        t1.y = bperm1(pa4, gB[k].y);
        PIN2(t1);
        pB[k] = t1;
      }
      float pnA = bperm1(pa4, nA);
      float pnB = bperm1(pa4, nB);
      const bool isp = l < (l ^ m);  // own columns are canonical-lower
      // 4 cross rotations; last use of pB is rot3, of pA is rot4 -> their
      // P-side updates are dead and skipped (UPDP=false).
      crossrot<true>(gA, nA, pA, pnA, isp);
      crossrot<true>(gB, nB, pB, pnB, isp);
      crossrot<false>(gA, nA, pB, pnB, isp);
      crossrot<false>(gB, nB, pA, pnA, isp);
    }
  }

  // ---- epilogue: lam_k = ||g_k||; out = F F^T with f_k = g_k lam^-3/4 ----
  float b2a = fmaxf(dotcols(gA, gA), 1e-20f);
  float b2b = fmaxf(dotcols(gB, gB), 1e-20f);
  const float la = sqrtf(b2a), lb = sqrtf(b2b);
  const float swa = 1.f / sqrtf(la * sqrtf(la));  // la^-3/4
  const float swb = 1.f / sqrtf(lb * sqrtf(lb));

  float* FTq = FT + q * 1088;  // [32][34]
#pragma unroll
  for (int k = 0; k < 16; ++k) {
    float2 w0 = {gA[k].x * swa, gB[k].x * swb};  // row 2k, cols ca,ca+1
    float2 w1 = {gA[k].y * swa, gB[k].y * swb};  // row 2k+1
    *(float2*)(FTq + (2 * k) * 34 + ca) = w0;
    *(float2*)(FTq + (2 * k + 1) * 34 + ca) = w1;
  }
  __syncthreads();

  // own F-rows ca, ca+1 into registers
  float ra[32], rb[32];
  {
    const float4* rowa = (const float4*)(FTq + ca * 34);
    const float4* rowb = (const float4*)(FTq + (ca + 1) * 34);
#pragma unroll
    for (int c4 = 0; c4 < 8; ++c4) {
      const float4 x = rowa[c4], y = rowb[c4];
      ra[4 * c4 + 0] = x.x; ra[4 * c4 + 1] = x.y;
      ra[4 * c4 + 2] = x.z; ra[4 * c4 + 3] = x.w;
      rb[4 * c4 + 0] = y.x; rb[4 * c4 + 1] = y.y;
      rb[4 * c4 + 2] = y.z; rb[4 * c4 + 3] = y.w;
    }
  }
  float* ob = out + (size_t)b * 1024;
  for (int i = 0; i < 32; ++i) {
    const float4* ri = (const float4*)(FTq + i * 34);
    float sa = 0.f, sb = 0.f;
#pragma unroll
    for (int c4 = 0; c4 < 8; ++c4) {
      const float4 v = ri[c4];  // broadcast within the 16-lane group
      sa = fmaf(v.x, ra[4 * c4 + 0], sa);
      sa = fmaf(v.y, ra[4 * c4 + 1], sa);
      sa = fmaf(v.z, ra[4 * c4 + 2], sa);
      sa = fmaf(v.w, ra[4 * c4 + 3], sa);
      sb = fmaf(v.x, rb[4 * c4 + 0], sb);
      sb = fmaf(v.y, rb[4 * c4 + 1], sb);
      sb = fmaf(v.z, rb[4 * c4 + 2], sb);
      sb = fmaf(v.w, rb[4 * c4 + 3], sb);
    }
    *(float2*)(ob + i * 32 + ca) = make_float2(sa, sb);  // coalesced
  }
}

// ---------------------------------------------------------------------------
extern "C" void kernel_launch(void* const* d_in, const int* in_sizes, int n_in,
                              void* d_out, int out_size, void* d_ws,
                              size_t ws_size, hipStream_t stream) {
  const float* x = (const float*)d_in[0];
  const float* W1 = (const float*)d_in[1];
  const float* b1 = (const float*)d_in[2];
  const float* WD = (const float*)d_in[3];
  const float* bD = (const float*)d_in[4];
  const float* WV = (const float*)d_in[5];
  const float* bV = (const float*)d_in[6];
  float* out = (float*)d_out;

  float* feat = out;                             // [16384,512] dead before out
  float* invD2 = (float*)d_ws;                   // [16384,32]
  float* V = (float*)d_ws + (size_t)16384 * 32;  // [16384,256]

  gemm_act<1><<<dim3(512 / 64, 16384 / 64), 256, 0, stream>>>(
      x, W1, b1, feat, 16384, 512, 128);
  gemm_act<2><<<dim3(1, 16384 / 64), 256, 0, stream>>>(
      feat, WD, bD, invD2, 16384, 32, 512);
  gemm_act<0><<<dim3(256 / 64, 16384 / 64), 256, 0, stream>>>(
      feat, WV, bV, V, 16384, 256, 512);
  woodbury_sqrtm_blk<<<16384 / 4, 64, 0, stream>>>(invD2, V, out);
}